// Round 3
// baseline (492.889 us; speedup 1.0000x reference)
//
#include <hip/hip_runtime.h>
#include <cstdint>
#include <cstddef>

// Problem constants
#define B_   4
#define C_   2048      // seq / conv channels
#define DM_  128       // d_model / conv length
#define H_   8
#define KK_  14336     // C_ * 7  (im2col K dimension)
#define N_   512       // B_ * DM_ (GEMM N dimension)

#define KSPLIT 8
#define KPB   1792     // KK_ / KSPLIT
#define NITER 56       // KPB / 32

typedef unsigned short u16;
typedef __attribute__((ext_vector_type(8))) short  s16x8;   // 8 x bf16 (4 VGPRs)
typedef __attribute__((ext_vector_type(4))) float  f32x4;

typedef const __attribute__((address_space(1))) void gvoid;
typedef __attribute__((address_space(3))) void lvoid;

__device__ __forceinline__ void gl2lds16(const void* g, void* l) {
    __builtin_amdgcn_global_load_lds((gvoid*)g, (lvoid*)l, 16, 0, 0);
}

__device__ __forceinline__ u16 f2bf(float f) {
    uint32_t u = __builtin_bit_cast(uint32_t, f);
    u += 0x7fffu + ((u >> 16) & 1u);   // round-to-nearest-even
    return (u16)(u >> 16);
}
__device__ __forceinline__ uint32_t pk2(float a, float b) {
    return (uint32_t)f2bf(a) | ((uint32_t)f2bf(b) << 16);
}

// ---------------------------------------------------------------- zero
__global__ __launch_bounds__(256) void zero_f4(float4* __restrict__ p, int n4) {
    int i = blockIdx.x * 256 + threadIdx.x;
    if (i < n4) p[i] = make_float4(0.f, 0.f, 0.f, 0.f);
}

// ---------------------------------------------------------------- im2col^T prep
__global__ __launch_bounds__(256) void prep_bimt(const float* __restrict__ key,
                                                 const float* __restrict__ value,
                                                 u16* __restrict__ bk,
                                                 u16* __restrict__ bv) {
    const float* src = blockIdx.z ? value : key;
    u16*         dst = blockIdx.z ? bv : bk;
    int gid = blockIdx.x * 256 + threadIdx.x;   // 0 .. 524287
    int cp = gid & 1023;                        // ci pair index
    int n  = gid >> 10;                         // 0 .. 511
    int b = n >> 7, l = n & 127;
    const float* s0 = src + (size_t)(b * C_ + cp * 2) * DM_;
    u16 hh[14];
#pragma unroll
    for (int r = 0; r < 2; ++r) {
#pragma unroll
        for (int t = 0; t < 7; ++t) {
            int j = l + t - 6;
            float v = (j >= 0) ? s0[r * DM_ + j] : 0.0f;
            hh[r * 7 + t] = f2bf(v);
        }
    }
    uint32_t* D = (uint32_t*)dst + (size_t)n * (KK_ / 2) + cp * 7;
#pragma unroll
    for (int i = 0; i < 7; ++i)
        D[i] = (uint32_t)hh[2 * i] | ((uint32_t)hh[2 * i + 1] << 16);
}

// ---------------------------------------------------------------- query prep (scale log2e/4, bf16)
__global__ __launch_bounds__(256) void prep_q(const float4* __restrict__ q, uint2* __restrict__ qb) {
    const float S = 0.25f * 1.44269504088896340736f;   // 1/sqrt(16) * log2(e)
    int i = blockIdx.x * 256 + threadIdx.x;            // 0 .. 262143
    float4 v = q[i];
    uint2 r;
    r.x = pk2(v.x * S, v.y * S);
    r.y = pk2(v.z * S, v.w * S);
    qb[i] = r;
}

// ---------------------------------------------------------------- conv as GEMM
// Y[m=co][n=(b,l)] += sum_k W[m][k] * BimT[n][k]. Tile 64M x 256N, splitK=8.
// Double-buffered LDS; B via global_load_lds (XOR-swizzled source); W fp32
// loaded dense (8 lanes/row x 16B -> 16 lines/instr), packed to bf16 in VALU.
// grid: x=32 Mtiles, y=2 Ntiles, z=16 (conv*8 + splitk); 1024 blocks = 4/CU.
__global__ __launch_bounds__(256, 4) void conv_gemm(
        const float* __restrict__ Wk, const float* __restrict__ Wv,
        const u16* __restrict__ Bk, const u16* __restrict__ Bv,
        float* __restrict__ Yk, float* __restrict__ Yv) {
    const int conv = blockIdx.z >> 3;
    const int sk   = blockIdx.z & 7;
    const float* W  = conv ? Wv : Wk;
    const u16*   Bm = conv ? Bv : Bk;
    float*       Y  = conv ? Yv : Yk;
    const int m0 = blockIdx.x * 64;
    const int n0 = blockIdx.y * 256;
    const int kbeg = sk * KPB;

    __shared__ __align__(16) u16 Al[2][64 * 32];    // 4 KB each; rows 64 B, swizzled 16B chunks
    __shared__ __align__(16) u16 Bl[2][256 * 32];   // 16 KB each

    const int tid = threadIdx.x;
    const int wave = tid >> 6, lane = tid & 63;
    const int l16 = lane & 15, quad = lane >> 4;
    const int wn0 = wave * 64;

    // ---- A (W) staging: 2 slots/thread; slot = row*8 + c8 (c8 = 8B bf16 sub-chunk)
    const int ar0 = tid >> 3,        ac0 = tid & 7;          // rows 0..31
    const int ar1 = (tid + 256) >> 3, ac1 = tid & 7;         // rows 32..63
    const float* wp0 = W + (size_t)(m0 + ar0) * KK_ + kbeg + ac0 * 4;
    const float* wp1 = W + (size_t)(m0 + ar1) * KK_ + kbeg + ac1 * 4;
    const int aoff0 = ar0 * 32 + (((ac0 >> 1) ^ ((ar0 >> 1) & 3)) * 8) + (ac0 & 1) * 4;
    const int aoff1 = ar1 * 32 + (((ac1 >> 1) ^ ((ar1 >> 1) & 3)) * 8) + (ac1 & 1) * 4;

    // ---- B staging via global_load_lds (4 passes/wave, 16 rows each)
    const u16* bgp[4];
    int boff[4];
    {
        const int br = lane >> 2, bs = lane & 3;
#pragma unroll
        for (int p = 0; p < 4; ++p) {
            int row = wave * 64 + p * 16 + br;
            int gc = (bs ^ ((row >> 1) & 3)) * 8;      // swizzled source chunk
            bgp[p] = Bm + (size_t)(n0 + row) * KK_ + kbeg + gc;
            boff[p] = (wave * 64 + p * 16) * 32;
        }
    }

    f32x4 acc[4][4];
#pragma unroll
    for (int i = 0; i < 4; ++i)
#pragma unroll
        for (int j = 0; j < 4; ++j) acc[i][j] = (f32x4){0.f, 0.f, 0.f, 0.f};

    float4 wA, wB;
    // ---- prologue: stage tile 0 into buffer 0, prefetch W(tile 1) to regs
    {
        float4 a0 = *(const float4*)(wp0);
        float4 a1 = *(const float4*)(wp1);
        *(uint2*)&Al[0][aoff0] = make_uint2(pk2(a0.x, a0.y), pk2(a0.z, a0.w));
        *(uint2*)&Al[0][aoff1] = make_uint2(pk2(a1.x, a1.y), pk2(a1.z, a1.w));
#pragma unroll
        for (int p = 0; p < 4; ++p)
            gl2lds16(bgp[p], &Bl[0][boff[p]]);
        wA = *(const float4*)(wp0 + 32);
        wB = *(const float4*)(wp1 + 32);
    }

    int c = 0;
    for (int ks = 0; ks < NITER; ++ks) {
        __syncthreads();   // drains tile-ks loads into buf c
        // frag reads FIRST
        s16x8 af[4];
#pragma unroll
        for (int fm = 0; fm < 4; ++fm) {
            int r = fm * 16 + l16;
            af[fm] = *(const s16x8*)&Al[c][r * 32 + ((quad ^ ((r >> 1) & 3)) * 8)];
        }
        s16x8 bfr[4];
#pragma unroll
        for (int fn = 0; fn < 4; ++fn) {
            int n = wn0 + fn * 16 + l16;
            bfr[fn] = *(const s16x8*)&Bl[c][n * 32 + ((quad ^ ((n >> 1) & 3)) * 8)];
        }
        // prefetch next tile into buf c^1
        const int kn  = (ks + 1 < NITER) ? ks + 1 : ks;
        const int kn2 = (ks + 2 < NITER) ? ks + 2 : 0;
#pragma unroll
        for (int p = 0; p < 4; ++p)
            gl2lds16(bgp[p] + (size_t)kn * 32, &Bl[c ^ 1][boff[p]]);
        *(uint2*)&Al[c ^ 1][aoff0] = make_uint2(pk2(wA.x, wA.y), pk2(wA.z, wA.w));
        *(uint2*)&Al[c ^ 1][aoff1] = make_uint2(pk2(wB.x, wB.y), pk2(wB.z, wB.w));
        wA = *(const float4*)(wp0 + (size_t)kn2 * 32);
        wB = *(const float4*)(wp1 + (size_t)kn2 * 32);
        // MFMA on buffer c
#pragma unroll
        for (int fm = 0; fm < 4; ++fm)
#pragma unroll
            for (int fn = 0; fn < 4; ++fn)
                acc[fm][fn] = __builtin_amdgcn_mfma_f32_16x16x32_bf16(af[fm], bfr[fn], acc[fm][fn], 0, 0, 0);
        c ^= 1;
    }

    // epilogue: split-K accumulate. C layout: col = lane&15, row = quad*4 + reg.
#pragma unroll
    for (int fm = 0; fm < 4; ++fm) {
        int m = m0 + fm * 16 + quad * 4;
#pragma unroll
        for (int fn = 0; fn < 4; ++fn) {
            int n = n0 + wn0 + fn * 16 + l16;
            int bb = n >> 7, ll = n & 127;
            float* yp = Y + ((size_t)(bb * C_ + m)) * DM_ + ll;
#pragma unroll
            for (int r = 0; r < 4; ++r)
                atomicAdd(yp + (size_t)r * DM_, acc[fm][fn][r]);
        }
    }
}

// ---------------------------------------------------------------- K/V prep for attention
// Kbf2[bh][rg=d>>3][key][8]  (16B per (key,rg), tile-contiguous for gl2lds)
// Vbf2[bh][d][key'], key' chunk-swizzled per 128-tile: c' = c ^ (d&15)
__global__ __launch_bounds__(256) void kv_prep(
        const float* __restrict__ Yk, const float* __restrict__ Yv,
        const float* __restrict__ bkb, const float* __restrict__ bvb,
        u16* __restrict__ Kbf2, u16* __restrict__ Vbf2) {
    int gid = blockIdx.x * 256 + threadIdx.x;   // 0 .. 65535
    int key = gid & 2047;
    int bh  = gid >> 11;
    int b = bh >> 3, h = bh & 7;
    size_t src = ((size_t)(b * C_ + key)) * DM_ + h * 16;
    float kb = bkb[key], vb = bvb[key];

    float4 k0 = *(const float4*)(Yk + src);
    float4 k1 = *(const float4*)(Yk + src + 4);
    float4 k2 = *(const float4*)(Yk + src + 8);
    float4 k3 = *(const float4*)(Yk + src + 12);
    uint4 pA, pB;
    pA.x = pk2(k0.x + kb, k0.y + kb); pA.y = pk2(k0.z + kb, k0.w + kb);
    pA.z = pk2(k1.x + kb, k1.y + kb); pA.w = pk2(k1.z + kb, k1.w + kb);
    pB.x = pk2(k2.x + kb, k2.y + kb); pB.y = pk2(k2.z + kb, k2.w + kb);
    pB.z = pk2(k3.x + kb, k3.y + kb); pB.w = pk2(k3.z + kb, k3.w + kb);
    *(uint4*)(Kbf2 + ((size_t)(bh * 2 + 0) * C_ + key) * 8) = pA;
    *(uint4*)(Kbf2 + ((size_t)(bh * 2 + 1) * C_ + key) * 8) = pB;

    float4 v0 = *(const float4*)(Yv + src);
    float4 v1 = *(const float4*)(Yv + src + 4);
    float4 v2 = *(const float4*)(Yv + src + 8);
    float4 v3 = *(const float4*)(Yv + src + 12);
    float vf[16] = {v0.x, v0.y, v0.z, v0.w, v1.x, v1.y, v1.z, v1.w,
                    v2.x, v2.y, v2.z, v2.w, v3.x, v3.y, v3.z, v3.w};
    int kt_off = key & ~127;
    int cch = (key >> 3) & 15, e = key & 7;
#pragma unroll
    for (int d = 0; d < 16; ++d) {
        u16* vr = Vbf2 + ((size_t)bh * 16 + d) * C_;
        vr[kt_off + ((cch ^ (d & 15)) << 3) + e] = f2bf(vf[d] + vb);
    }
}

// ---------------------------------------------------------------- flash attention (no-max online softmax)
// grid: x = 32 q-tiles (64 rows), y = 32 (b*8+h). Block 256 = 4 waves; wave owns 16 q-rows.
// Scores bounded (|s|<~30 in exp2 domain) so exp2 without max-subtraction is safe;
// denominator accumulated per-lane, reduced once at the end.
#define PSTR 140   // Pl row stride in u16 (2-way banks for b16 writes; b64-aligned reads)
__global__ __launch_bounds__(256, 4) void attn_k(
        const u16* __restrict__ Kbf2, const u16* __restrict__ Vbf2,
        const u16* __restrict__ qb, u16* __restrict__ att) {
    const int q0 = blockIdx.x * 64;
    const int bh = blockIdx.y;
    const int b = bh >> 3, h = bh & 7;

    __shared__ __align__(16) u16 Kl[2 * 128 * 8];    // 4 KB: [rg][key][8]
    __shared__ __align__(16) u16 Vl[16 * 128];       // 4 KB: [d][key'] (swizzle baked in source)
    __shared__ __align__(16) u16 Pl[64 * PSTR];      // 17.5 KB

    const int tid = threadIdx.x;
    const int wave = tid >> 6, lane = tid & 63;
    const int l16 = lane & 15, quad = lane >> 4;

    // staging pointers: slot = tid covers one 16B chunk of each tile
    const u16* ksrc = Kbf2 + ((size_t)(bh * 2 + (tid >> 7)) * C_ + (tid & 127)) * 8;
    const u16* vsrc = Vbf2 + ((size_t)bh * 16 + (tid >> 4)) * C_ + (tid & 15) * 8;
    u16* kdst = &Kl[(size_t)wave * 64 * 8];
    u16* vdst = &Vl[(size_t)wave * 64 * 8];

    // Q fragment (A-layout): m = lane&15, k(d) = quad*8+j ; d>=16 zero padding.
    s16x8 qf = {};
    if (quad < 2) {
        const u16* qp = qb + ((size_t)(b * C_ + q0 + wave * 16 + l16)) * DM_ + h * 16 + quad * 8;
        qf = *(const s16x8*)qp;
    }
    f32x4 o = (f32x4){0.f, 0.f, 0.f, 0.f};
    float ps[4] = {0.f, 0.f, 0.f, 0.f};

    for (int kt = 0; kt < 16; ++kt) {
        const int k0 = kt * 128;
        __syncthreads();                       // prev readers of Kl/Vl done
        gl2lds16(ksrc + (size_t)k0 * 8, kdst);
        gl2lds16(vsrc + k0, vdst);
        __syncthreads();                       // staged (drains LDS-DMA)

        // S = Q K^T : 8 N-frags of 16 keys
        f32x4 sf[8];
#pragma unroll
        for (int fn = 0; fn < 8; ++fn) {
            s16x8 kb = {};
            if (quad < 2) kb = *(const s16x8*)&Kl[quad * 1024 + (fn * 16 + l16) * 8];
            sf[fn] = __builtin_amdgcn_mfma_f32_16x16x32_bf16(qf, kb, (f32x4){0.f, 0.f, 0.f, 0.f}, 0, 0, 0);
        }

        // p = exp2(s') (q pre-scaled by log2e/4); accumulate denominator per lane
#pragma unroll
        for (int fn = 0; fn < 8; ++fn) {
#pragma unroll
            for (int r = 0; r < 4; ++r) {
                float p = exp2f(sf[fn][r]);
                ps[r] += p;
                Pl[(wave * 16 + quad * 4 + r) * PSTR + fn * 16 + l16] = f2bf(p);
            }
        }
        // Pl rows are wave-private: same-wave ds_write -> ds_read needs no barrier.
        // O += P V  (K-dim = 128 keys, 4 MFMAs)
#pragma unroll
        for (int ko = 0; ko < 4; ++ko) {
            const u16* pb = &Pl[(wave * 16 + l16) * PSTR + ko * 32 + quad * 8];
            uint2 lo = *(const uint2*)pb;
            uint2 hi = *(const uint2*)(pb + 4);
            s16x8 pa = __builtin_bit_cast(s16x8, make_uint4(lo.x, lo.y, hi.x, hi.y));
            s16x8 vb = *(const s16x8*)&Vl[l16 * 128 + (((ko * 4 + quad) ^ l16) & 15) * 8];
            o = __builtin_amdgcn_mfma_f32_16x16x32_bf16(pa, vb, o, 0, 0, 0);
        }
    }

    // final denominator: reduce over the 16 column-lanes (butterfly -> all lanes)
#pragma unroll
    for (int r = 0; r < 4; ++r) {
        float t = ps[r];
        t += __shfl_xor(t, 1);
        t += __shfl_xor(t, 2);
        t += __shfl_xor(t, 4);
        t += __shfl_xor(t, 8);
        ps[r] = t;
    }
#pragma unroll
    for (int r = 0; r < 4; ++r) {
        int row = q0 + wave * 16 + quad * 4 + r;
        att[((size_t)(b * C_ + row)) * DM_ + h * 16 + l16] = f2bf(o[r] / ps[r]);
    }
}

// ---------------------------------------------------------------- final linear: out = att @ lw^T + lb
__global__ __launch_bounds__(256, 2) void lin_k(
        const u16* __restrict__ att, const float* __restrict__ lw,
        const float* __restrict__ lb, float* __restrict__ out) {
    const int r0 = blockIdx.x * 32;
    __shared__ __align__(16) u16 Wl[128 * 136];
    __shared__ __align__(16) u16 Atl[32 * 136];
    const int tid = threadIdx.x;
    const int wave = tid >> 6, lane = tid & 63;
    const int l16 = lane & 15, quad = lane >> 4;

    {   // stage lin_w -> bf16, layout Wl[j][i]
        int j = tid >> 1, half = tid & 1;
        const float* src = lw + (size_t)j * DM_ + half * 64;
        u16* dstp = &Wl[j * 136 + half * 64];
#pragma unroll
        for (int c = 0; c < 8; ++c) {
            float4 f0 = *(const float4*)(src + c * 8);
            float4 f1 = *(const float4*)(src + c * 8 + 4);
            uint4 p;
            p.x = pk2(f0.x, f0.y); p.y = pk2(f0.z, f0.w);
            p.z = pk2(f1.x, f1.y); p.w = pk2(f1.z, f1.w);
            *(uint4*)(dstp + c * 8) = p;
        }
    }
    {   // stage att tile
        int row = tid >> 3, seg = tid & 7;
        const uint4* src = (const uint4*)(att + ((size_t)(r0 + row)) * DM_ + seg * 16);
        uint4 a0 = src[0], a1 = src[1];
        *(uint4*)&Atl[row * 136 + seg * 16]     = a0;
        *(uint4*)&Atl[row * 136 + seg * 16 + 8] = a1;
    }
    __syncthreads();

    const int wn0 = wave * 32;
    f32x4 acc[2][2];
#pragma unroll
    for (int i = 0; i < 2; ++i)
#pragma unroll
        for (int j = 0; j < 2; ++j) acc[i][j] = (f32x4){0.f, 0.f, 0.f, 0.f};
#pragma unroll
    for (int ko = 0; ko < 4; ++ko) {
        s16x8 af[2], bf[2];
#pragma unroll
        for (int fm = 0; fm < 2; ++fm)
            af[fm] = *(const s16x8*)&Atl[(fm * 16 + l16) * 136 + ko * 32 + quad * 8];
#pragma unroll
        for (int fn = 0; fn < 2; ++fn)
            bf[fn] = *(const s16x8*)&Wl[(wn0 + fn * 16 + l16) * 136 + ko * 32 + quad * 8];
#pragma unroll
        for (int fm = 0; fm < 2; ++fm)
#pragma unroll
            for (int fn = 0; fn < 2; ++fn)
                acc[fm][fn] = __builtin_amdgcn_mfma_f32_16x16x32_bf16(af[fm], bf[fn], acc[fm][fn], 0, 0, 0);
    }
#pragma unroll
    for (int fm = 0; fm < 2; ++fm) {
#pragma unroll
        for (int fn = 0; fn < 2; ++fn) {
            int col = wn0 + fn * 16 + l16;
            float bias = lb[col];
#pragma unroll
            for (int r = 0; r < 4; ++r) {
                int row = r0 + fm * 16 + quad * 4 + r;
                out[(size_t)row * DM_ + col] = acc[fm][fn][r] + bias;
            }
        }
    }
}

// ---------------------------------------------------------------- launcher
extern "C" void kernel_launch(void* const* d_in, const int* in_sizes, int n_in,
                              void* d_out, int out_size, void* d_ws, size_t ws_size,
                              hipStream_t stream) {
    const float* query = (const float*)d_in[0];
    const float* key   = (const float*)d_in[1];
    const float* value = (const float*)d_in[2];
    const float* wk    = (const float*)d_in[3];
    const float* bk    = (const float*)d_in[4];
    const float* wv    = (const float*)d_in[5];
    const float* bv    = (const float*)d_in[6];
    const float* lw    = (const float*)d_in[7];
    const float* lb    = (const float*)d_in[8];
    float* out = (float*)d_out;

    char* ws = (char*)d_ws;
    u16*   bimt_k = (u16*)(ws);                       // 14,680,064 B
    u16*   bimt_v = (u16*)(ws + 14680064);            // 14,680,064 B
    float* yk     = (float*)(ws + 29360128);          // 4 MB
    float* yv     = (float*)(ws + 33554432);          // 4 MB
    u16*   qbf    = (u16*)(ws + 37748736);            // 2 MB
    u16*   att    = (u16*)(ws + 39845888);            // 2 MB
    u16*   kbf2   = (u16*)(ws + 41943040);            // 2 MB
    u16*   vbf2   = (u16*)(ws + 44040192);            // 2 MB  (total ~46 MB)

    // 1) zero conv accumulators (yk & yv contiguous: 8 MB = 524288 float4)
    zero_f4<<<2048, 256, 0, stream>>>((float4*)yk, 524288);
    // 2) im2col^T bf16 for key & value
    prep_bimt<<<dim3(2048, 1, 2), 256, 0, stream>>>(key, value, bimt_k, bimt_v);
    // 3) query -> bf16 * log2e/4
    prep_q<<<1024, 256, 0, stream>>>((const float4*)query, (uint2*)qbf);
    // 4) both convs as split-K GEMM (dense W loads, 4 blocks/CU)
    conv_gemm<<<dim3(32, 2, 16), 256, 0, stream>>>(wk, wv, bimt_k, bimt_v, yk, yv);
    // 5) bias + bf16 + layout prep for attention K/V
    kv_prep<<<256, 256, 0, stream>>>(yk, yv, bk, bv, kbf2, vbf2);
    // 6) flash attention
    attn_k<<<dim3(32, 32), 256, 0, stream>>>(kbf2, vbf2, qbf, att);
    // 7) output projection
    lin_k<<<256, 256, 0, stream>>>(att, lw, lb, out);
}